// Round 11
// baseline (212.217 us; speedup 1.0000x reference)
//
#include <hip/hip_runtime.h>

#define BB 8
#define HH 1024
#define WW 1024
#define HW (HH*WW)
#define PI_F 3.14159265358979323846f

static __device__ __forceinline__ void gload16(const float* g, float* l)
{
    __builtin_amdgcn_global_load_lds(
        (const __attribute__((address_space(1))) void*)g,
        (__attribute__((address_space(3))) void*)l,
        16, 0, 0);
}

// bf16 pack/unpack (round-to-nearest-even)
static __device__ __forceinline__ unsigned short f2bf(float f)
{
    unsigned u = __float_as_uint(f);
    return (unsigned short)((u + 0x7fffu + ((u >> 16) & 1u)) >> 16);
}
static __device__ __forceinline__ float bf2f(unsigned short h)
{
    return __uint_as_float(((unsigned)h) << 16);
}

// ---------------------------------------------------------------------------
// Twiddle table + NRM zeroing. Per-stage concatenated: stage with half-span
// len at offset (1024-2*len), len entries exp(-i*pi*j/len)
// ---------------------------------------------------------------------------
__global__ __launch_bounds__(256) void k_twid(float2* __restrict__ tw,
                                              float* __restrict__ nrm)
{
    int tid = blockIdx.x * 256 + threadIdx.x;   // 1024 threads
    if (tid < 16) nrm[tid] = 0.0f;
    for (int len = 512; len >= 1; len >>= 1) {
        int off = 1024 - 2 * len;
        float fac = -PI_F / (float)len;
        for (int j = tid; j < len; j += 1024) {
            float sn, cs;
            sincosf(fac * (float)j, &sn, &cs);
            tw[off + j] = make_float2(cs, sn);
        }
    }
}

// ---------------------------------------------------------------------------
// Fused 3x diffusion of f_u/f_v + L2 norm — full-width band register-march.
// Output bf16 (ushort): halves the F1 write. Norm accumulated in fp32.
// ---------------------------------------------------------------------------
#define RBAND 8
#define RAWROWS 14          // RBAND + 6

__global__ __launch_bounds__(256) void k_diff3(const float* __restrict__ su,
                                               const float* __restrict__ sv,
                                               unsigned short* __restrict__ dst,
                                               float* __restrict__ norms)
{
    __shared__ __align__(16) float A[RAWROWS * WW];   // 56 KB
    __shared__ float wsum[4];

    int bid = blockIdx.x;
    int work = (bid & 7) * 256 + (bid >> 3);
    int z = work >> 7;            // f*8+b, 0..15
    int band = work & 127;
    int f = z >> 3, b = z & 7;
    const float* s = ((f == 0) ? su : sv) + (size_t)b * HW;
    unsigned short* d = dst + (size_t)z * HW;
    int yb = band * RBAND;
    int tid = threadIdx.x;
    int w = tid >> 6, lane = tid & 63;

    for (int c = w; c < RAWROWS * 4; c += 4) {
        int row = c >> 2, seg = c & 3;
        const float* g = s + (size_t)((yb - 3 + row) & (HH - 1)) * WW
                           + (seg << 8) + (lane << 2);
        gload16(g, &A[(c << 8) + (lane << 2)]);
    }
    __syncthreads();

    const char* Ab = (const char*)A;
    int xq = tid << 4;
    int om = (xq - 16) & 4095;
    int op = (xq + 16) & 4095;

    float r[3][12];
    float i1[3][8];
    float i2[3][6];
    float sq = 0.0f;

    #pragma unroll
    for (int j = 0; j < RAWROWS; ++j) {
        {
            float4 a = *(const float4*)(Ab + j * 4096 + om);
            float4 bq = *(const float4*)(Ab + j * 4096 + xq);
            float4 cq = *(const float4*)(Ab + j * 4096 + op);
            float* rr = r[j % 3];
            rr[0] = a.x; rr[1] = a.y; rr[2] = a.z; rr[3] = a.w;
            rr[4] = bq.x; rr[5] = bq.y; rr[6] = bq.z; rr[7] = bq.w;
            rr[8] = cq.x; rr[9] = cq.y; rr[10] = cq.z; rr[11] = cq.w;
        }
        if (j >= 2) {
            const float* ru = r[(j - 2) % 3];
            const float* rc = r[(j - 1) % 3];
            const float* rd = r[j % 3];
            float* o = i1[(j - 1) % 3];
            #pragma unroll
            for (int k = 0; k < 8; ++k) {
                float c0 = rc[k + 2];
                o[k] = c0 + 0.1f * (rc[k + 1] + rc[k + 3] + ru[k + 2] + rd[k + 2] - 4.0f * c0);
            }
        }
        if (j >= 4) {
            const float* u = i1[(j - 3) % 3];
            const float* c = i1[(j - 2) % 3];
            const float* dd = i1[(j - 1) % 3];
            float* o = i2[(j - 2) % 3];
            #pragma unroll
            for (int k = 0; k < 6; ++k) {
                float c0 = c[k + 1];
                o[k] = c0 + 0.1f * (c[k] + c[k + 2] + u[k + 1] + dd[k + 1] - 4.0f * c0);
            }
        }
        if (j >= 6) {
            const float* u = i2[(j - 4) % 3];
            const float* c = i2[(j - 3) % 3];
            const float* dd = i2[(j - 2) % 3];
            float ov[4];
            #pragma unroll
            for (int k = 0; k < 4; ++k) {
                float c0 = c[k + 1];
                ov[k] = c0 + 0.1f * (c[k] + c[k + 2] + u[k + 1] + dd[k + 1] - 4.0f * c0);
            }
            ushort4 o16 = make_ushort4(f2bf(ov[0]), f2bf(ov[1]), f2bf(ov[2]), f2bf(ov[3]));
            *(ushort4*)(d + (size_t)(yb + j - 6) * WW + (tid << 2)) = o16;
            sq += ov[0] * ov[0] + ov[1] * ov[1] + ov[2] * ov[2] + ov[3] * ov[3];
        }
    }

    #pragma unroll
    for (int o = 32; o > 0; o >>= 1) sq += __shfl_down(sq, o, 64);
    if (lane == 0) wsum[w] = sq;
    __syncthreads();
    if (tid == 0)
        atomicAdd(&norms[z], wsum[0] + wsum[1] + wsum[2] + wsum[3]);
}

// ---------------------------------------------------------------------------
// Star velocities — quad-vectorized, block = one full row. F read as bf16.
// Row index XCD-swizzled for L2 halo locality.
// ---------------------------------------------------------------------------
__global__ __launch_bounds__(256) void k_star(const float* __restrict__ X,
                                              const float* __restrict__ beta,
                                              const unsigned short* __restrict__ F,
                                              const float* __restrict__ norms,
                                              float* __restrict__ UV)
{
    int b = blockIdx.y;
    int yx = blockIdx.x;
    int y = (yx & 7) * 128 + (yx >> 3);   // bijective XCD swizzle (1024 % 8 == 0)
    int tid = threadIdx.x;
    int lane = tid & 63;
    int xq = tid << 2;
    const float* u = X + (size_t)(b * 3 + 0) * HW;
    const float* v = X + (size_t)(b * 3 + 1) * HW;
    const float* p = X + (size_t)(b * 3 + 2) * HW;
    int yr = y * WW, ym = ((y - 1) & (HH - 1)) * WW, yp = ((y + 1) & (HH - 1)) * WW;

    float4 ucq = *(const float4*)(u + yr + xq);
    float4 uuq = *(const float4*)(u + ym + xq);
    float4 udq = *(const float4*)(u + yp + xq);
    float4 vcq = *(const float4*)(v + yr + xq);
    float4 vuq = *(const float4*)(v + ym + xq);
    float4 vdq = *(const float4*)(v + yp + xq);
    float4 pcq = *(const float4*)(p + yr + xq);
    float4 puq = *(const float4*)(p + ym + xq);
    float4 pdq = *(const float4*)(p + yp + xq);
    ushort4 fuq = *(const ushort4*)(F + (size_t)(0 * BB + b) * HW + yr + xq);
    ushort4 fvq = *(const ushort4*)(F + (size_t)(1 * BB + b) * HW + yr + xq);

    float ulf = __shfl_up(ucq.w, 1, 64), urt = __shfl_down(ucq.x, 1, 64);
    float vlf = __shfl_up(vcq.w, 1, 64), vrt = __shfl_down(vcq.x, 1, 64);
    float plf = __shfl_up(pcq.w, 1, 64), prt = __shfl_down(pcq.x, 1, 64);
    if (lane == 0)  { int xm = (xq - 1) & (WW - 1); ulf = u[yr + xm]; vlf = v[yr + xm]; plf = p[yr + xm]; }
    if (lane == 63) { int xp = (xq + 4) & (WW - 1); urt = u[yr + xp]; vrt = v[yr + xp]; prt = p[yr + xp]; }

    float ue[6] = { ulf, ucq.x, ucq.y, ucq.z, ucq.w, urt };
    float ve[6] = { vlf, vcq.x, vcq.y, vcq.z, vcq.w, vrt };
    float pe[6] = { plf, pcq.x, pcq.y, pcq.z, pcq.w, prt };
    float uu_[4] = { uuq.x, uuq.y, uuq.z, uuq.w };
    float ud_[4] = { udq.x, udq.y, udq.z, udq.w };
    float vu_[4] = { vuq.x, vuq.y, vuq.z, vuq.w };
    float vd_[4] = { vdq.x, vdq.y, vdq.z, vdq.w };
    float pu_[4] = { puq.x, puq.y, puq.z, puq.w };
    float pd_[4] = { pdq.x, pdq.y, pdq.z, pdq.w };
    float fu_[4] = { bf2f(fuq.x), bf2f(fuq.y), bf2f(fuq.z), bf2f(fuq.w) };
    float fv_[4] = { bf2f(fvq.x), bf2f(fvq.y), bf2f(fvq.z), bf2f(fvq.w) };

    float sb = sqrtf(beta[b]);
    float inu = 1.0f / fmaxf(sqrtf(norms[b]), 1e-12f);
    float inv = 1.0f / fmaxf(sqrtf(norms[BB + b]), 1e-12f);

    float4 un4, vn4;
    float* unp = (float*)&un4;
    float* vnp = (float*)&vn4;
    #pragma unroll
    for (int k = 0; k < 4; ++k) {
        float ucc = ue[k + 1], vcc = ve[k + 1];
        float adv_u = ucc * (0.5f * (ue[k + 2] - ue[k])) + vcc * (0.5f * (ud_[k] - uu_[k]));
        float adv_v = ucc * (0.5f * (ve[k + 2] - ve[k])) + vcc * (0.5f * (vd_[k] - vu_[k]));
        float lap_u = ue[k] + ue[k + 2] + uu_[k] + ud_[k] - 4.0f * ucc;
        float lap_v = ve[k] + ve[k + 2] + vu_[k] + vd_[k] - 4.0f * vcc;
        float dpdx = 0.5f * (pe[k + 2] - pe[k]);
        float dpdy = 0.5f * (pd_[k] - pu_[k]);
        unp[k] = ucc + 0.01f * (-adv_u + 0.01f * lap_u - dpdx) + sb * fu_[k] * inu;
        vnp[k] = vcc + 0.01f * (-adv_v + 0.01f * lap_v - dpdy) + sb * fv_[k] * inv;
    }

    *(float4*)(UV + (size_t)(0 * BB + b) * HW + yr + xq) = un4;
    *(float4*)(UV + (size_t)(1 * BB + b) * HW + yr + xq) = vn4;
}

// ---------------------------------------------------------------------------
// float2-based FFT helpers (length 1024, LDS, 256 threads, block-wide)
// ---------------------------------------------------------------------------
static __device__ __forceinline__ void fft_dif2(float2* d, const float2* tw)
{
    int t = threadIdx.x;
    for (int s = 9; s >= 0; --s) {
        int len = 1 << s;
        int off = 1024 - 2 * len;
        __syncthreads();
        #pragma unroll
        for (int k = 0; k < 2; ++k) {
            int bt = t + (k << 8);
            int j = bt & (len - 1);
            int i = ((bt >> s) << (s + 1)) | j;
            float2 u = d[i], v = d[i + len], w = tw[off + j];
            d[i] = make_float2(u.x + v.x, u.y + v.y);
            float dr = u.x - v.x, di = u.y - v.y;
            d[i + len] = make_float2(dr * w.x - di * w.y, dr * w.y + di * w.x);
        }
    }
}

// split re/im inverse DIT (bit-reversed in -> natural out, unnormalized):
// 4B elements keep worst-case LDS conflicts at 4-way (float2 version is 8-way)
static __device__ __forceinline__ void fft_dit_inv_s(float* re, float* im,
                                                     const float2* tw)
{
    int t = threadIdx.x;
    for (int s = 0; s <= 9; ++s) {
        int len = 1 << s;
        int off = 1024 - 2 * len;
        __syncthreads();
        #pragma unroll
        for (int k = 0; k < 2; ++k) {
            int bt = t + (k << 8);
            int j = bt & (len - 1);
            int i = ((bt >> s) << (s + 1)) | j;
            float ur = re[i], ui = im[i];
            float vr = re[i + len], vi = im[i + len];
            float2 w = tw[off + j];   // conj(w)
            float tr = vr * w.x + vi * w.y;
            float ti = vi * w.x - vr * w.y;
            re[i] = ur + tr;       im[i] = ui + ti;
            re[i + len] = ur - tr; im[i + len] = ui - ti;
        }
    }
}

// ---------------------------------------------------------------------------
// Fused divergence + forward row FFT. Block = (row y, pair q). Row swizzled.
// ---------------------------------------------------------------------------
__global__ __launch_bounds__(256) void k_divfft(const float* __restrict__ UV,
                                                float2* __restrict__ dst,
                                                const float2* __restrict__ tw)
{
    __shared__ __align__(16) float2 data[1024];
    __shared__ __align__(16) float2 twl[1024];
    __shared__ __align__(16) float us0[1024], us1[1024];
    int yx = blockIdx.x, q = blockIdx.y;
    int y = (yx & 7) * 128 + (yx >> 3);   // XCD swizzle
    int b0 = 2 * q, b1 = 2 * q + 1;
    int tid = threadIdx.x, w = tid >> 6, lane = tid & 63;
    int yr = y * WW, ym = ((y - 1) & (HH - 1)) * WW, yp = ((y + 1) & (HH - 1)) * WW;
    const float* u0 = UV + (size_t)b0 * HW;
    const float* v0 = UV + (size_t)(BB + b0) * HW;
    const float* u1 = UV + (size_t)b1 * HW;
    const float* v1 = UV + (size_t)(BB + b1) * HW;

    gload16(u0 + yr + (w << 8) + (lane << 2), &us0[(w << 8) + (lane << 2)]);
    gload16(u1 + yr + (w << 8) + (lane << 2), &us1[(w << 8) + (lane << 2)]);

    for (int j = tid; j < 1024; j += 256) twl[j] = tw[j];

    int xq = tid << 2;
    float4 v0u = *(const float4*)(v0 + ym + xq);
    float4 v0d = *(const float4*)(v0 + yp + xq);
    float4 v1u = *(const float4*)(v1 + ym + xq);
    float4 v1d = *(const float4*)(v1 + yp + xq);
    __syncthreads();   // drains DMA (vmcnt) + twl

    float4 c0 = *(const float4*)&us0[xq];
    float4 c1 = *(const float4*)&us1[xq];
    float lf0 = us0[(xq - 1) & 1023], rt0 = us0[(xq + 4) & 1023];
    float lf1 = us1[(xq - 1) & 1023], rt1 = us1[(xq + 4) & 1023];
    float u0e[6] = { lf0, c0.x, c0.y, c0.z, c0.w, rt0 };
    float u1e[6] = { lf1, c1.x, c1.y, c1.z, c1.w, rt1 };
    float v0u_[4] = { v0u.x, v0u.y, v0u.z, v0u.w };
    float v0d_[4] = { v0d.x, v0d.y, v0d.z, v0d.w };
    float v1u_[4] = { v1u.x, v1u.y, v1u.z, v1u.w };
    float v1d_[4] = { v1d.x, v1d.y, v1d.z, v1d.w };
    #pragma unroll
    for (int k = 0; k < 4; ++k) {
        float d0 = 0.5f * (u0e[k + 2] - u0e[k]) + 0.5f * (v0d_[k] - v0u_[k]);
        float d1 = 0.5f * (u1e[k + 2] - u1e[k]) + 0.5f * (v1d_[k] - v1u_[k]);
        data[xq + k] = make_float2(d0, d1);
    }

    fft_dif2(data, twl);
    __syncthreads();
    size_t base = (size_t)((q << 10) + y) << 10;
    float4* dst4 = (float4*)(dst + base);
    float4* dat4 = (float4*)data;
    dst4[2 * tid] = dat4[2 * tid];
    dst4[2 * tid + 1] = dat4[2 * tid + 1];
}

// ---------------------------------------------------------------------------
// Fused column pass: CT=8 columns/block, 512 threads (8 waves), 2 blocks/CU.
// Per-wave 1024-pt FFT, wave-local; Poisson scale; inverse FFT; in place.
// ---------------------------------------------------------------------------
#define CT 8
#define CSTR 1026

__global__ __launch_bounds__(512) void k_colpass(float2* __restrict__ spec,
                                                 const float2* __restrict__ tw)
{
    __shared__ __align__(16) float2 colbuf[CT * CSTR];   // 65664 B
    __shared__ __align__(16) float2 twl[1024];           // 8192 B
    int tile = blockIdx.x, q = blockIdx.y;
    int i0 = tile * CT;
    int tid = threadIdx.x, lane = tid & 63, w = tid >> 6;
    size_t qb = (size_t)q * HW;

    twl[tid] = tw[tid];
    twl[tid + 512] = tw[tid + 512];

    float2* g = spec + qb;
    #pragma unroll 4
    for (int pass = 0; pass < 16; ++pass) {
        int n = (pass << 9) + tid;
        int r = n >> 3, c = n & 7;
        colbuf[c * CSTR + r] = g[(size_t)r * 1024 + i0 + c];
    }
    __syncthreads();

    // --- per-wave column FFT (column i0+w) ---------------------------------
    float2* d = colbuf + w * CSTR;
    int i = i0 + w;
    int kx = __brev((unsigned)i) >> 22;
    int fx = (kx < 512) ? kx : kx - 1024;
    float fx2 = (float)(fx * fx);

    for (int s = 9; s >= 0; --s) {
        int len = 1 << s, off = 1024 - 2 * len;
        asm volatile("s_waitcnt lgkmcnt(0)" ::: "memory");
        __builtin_amdgcn_sched_barrier(0);
        #pragma unroll
        for (int k = 0; k < 8; ++k) {
            int bt = lane + (k << 6);
            int j = bt & (len - 1);
            int ii = ((bt >> s) << (s + 1)) | j;
            float2 u = d[ii], v = d[ii + len], wv = twl[off + j];
            d[ii] = make_float2(u.x + v.x, u.y + v.y);
            float dr = u.x - v.x, di = u.y - v.y;
            d[ii + len] = make_float2(dr * wv.x - di * wv.y, dr * wv.y + di * wv.x);
        }
    }
    asm volatile("s_waitcnt lgkmcnt(0)" ::: "memory");
    __builtin_amdgcn_sched_barrier(0);
    const float cc = -1.0f / (4.0f * PI_F * PI_F * 1024.0f * 1024.0f); // incl. 1/(H*W)
    #pragma unroll
    for (int k = 0; k < 16; ++k) {
        int kk = lane + (k << 6);
        int ky = __brev((unsigned)kk) >> 22;
        int fy = (ky < 512) ? ky : ky - 1024;
        float k2 = fx2 + (float)(fy * fy);
        float s = (k2 > 0.0f) ? (cc / k2) : 0.0f;   // DC zeroed
        float2 v = d[kk];
        d[kk] = make_float2(v.x * s, v.y * s);
    }
    for (int s = 0; s <= 9; ++s) {
        int len = 1 << s, off = 1024 - 2 * len;
        asm volatile("s_waitcnt lgkmcnt(0)" ::: "memory");
        __builtin_amdgcn_sched_barrier(0);
        #pragma unroll
        for (int k = 0; k < 8; ++k) {
            int bt = lane + (k << 6);
            int j = bt & (len - 1);
            int ii = ((bt >> s) << (s + 1)) | j;
            float2 u = d[ii], v = d[ii + len], wv = twl[off + j];   // conj(w)
            float tr = v.x * wv.x + v.y * wv.y;
            float ti = v.y * wv.x - v.x * wv.y;
            d[ii] = make_float2(u.x + tr, u.y + ti);
            d[ii + len] = make_float2(u.x - tr, u.y - ti);
        }
    }
    asm volatile("s_waitcnt lgkmcnt(0)" ::: "memory");
    __builtin_amdgcn_sched_barrier(0);
    __syncthreads();

    #pragma unroll 4
    for (int pass = 0; pass < 16; ++pass) {
        int n = (pass << 9) + tid;
        int r = n >> 3, c = n & 7;
        g[(size_t)r * 1024 + i0 + c] = colbuf[c * CSTR + r];
    }
}

// ---------------------------------------------------------------------------
// Fused inverse row FFT + final projection. Band index XCD-swizzled.
// Ring stored as SPLIT re/im float arrays: butterfly worst-case conflict
// drops 8-way -> 4-way, and emit float4 ring reads are wave-contiguous
// (conflict-free). Spectrum loaded via plain coalesced float4 loads and
// deinterleaved (contiguous b128 LDS writes).
// ---------------------------------------------------------------------------
#define FBAND 4

__global__ __launch_bounds__(256) void k_ifinal(const float2* __restrict__ spec,
                                                const float* __restrict__ UV,
                                                const float* __restrict__ X,
                                                float* __restrict__ out,
                                                const float2* __restrict__ tw)
{
    __shared__ float rre[3][1024], rim[3][1024];     // 24 KB split ring
    __shared__ __align__(16) float2 twl[1024];       // 8 KB
    int bx = blockIdx.x, q = blockIdx.y;
    int band = (bx & 7) * 32 + (bx >> 3);   // XCD swizzle (256 % 8 == 0)
    int b0 = 2 * q, b1 = 2 * q + 1;
    int y0 = band * FBAND;
    int tid = threadIdx.x;

    for (int j = tid; j < 1024; j += 256) twl[j] = tw[j];

    size_t sbase = (size_t)q * HW;
    const float* u0 = UV + (size_t)(0 * BB + b0) * HW;
    const float* v0 = UV + (size_t)(BB + b0) * HW;
    const float* u1 = UV + (size_t)(0 * BB + b1) * HW;
    const float* v1 = UV + (size_t)(BB + b1) * HW;
    const float* p0 = X + (size_t)(b0 * 3 + 2) * HW;
    const float* p1 = X + (size_t)(b1 * 3 + 2) * HW;
    float* o_u0 = out + (size_t)(b0 * 3 + 0) * HW;
    float* o_v0 = out + (size_t)(b0 * 3 + 1) * HW;
    float* o_p0 = out + (size_t)(b0 * 3 + 2) * HW;
    float* o_u1 = out + (size_t)(b1 * 3 + 0) * HW;
    float* o_v1 = out + (size_t)(b1 * 3 + 1) * HW;
    float* o_p1 = out + (size_t)(b1 * 3 + 2) * HW;

    for (int rr = 0; rr < FBAND + 2; ++rr) {
        int yg = (y0 - 1 + rr) & (HH - 1);
        float* re = rre[rr % 3];
        float* im = rim[rr % 3];

        __syncthreads();   // prior emit readers done before overwriting oldest slot
        {
            // load spectrum row: 2x float4 (4 complex) per thread, deinterleave
            const float4* g4 = (const float4*)(spec + sbase + (size_t)yg * 1024);
            float4 a = g4[2 * tid], bq = g4[2 * tid + 1];
            int base = tid << 2;
            re[base]     = a.x;  im[base]     = a.y;
            re[base + 1] = a.z;  im[base + 1] = a.w;
            re[base + 2] = bq.x; im[base + 2] = bq.y;
            re[base + 3] = bq.z; im[base + 3] = bq.w;
        }
        fft_dit_inv_s(re, im, twl);   // first stage barrier fences the writes
        __syncthreads();              // slot complete

        if (rr >= 2) {
            int ye = y0 + rr - 2;
            const float* cR = rre[(rr - 1) % 3];   // row ye, batch b0
            const float* cI = rim[(rr - 1) % 3];   // row ye, batch b1
            const float* uR = rre[(rr - 2) % 3];   // row ye-1
            const float* uI = rim[(rr - 2) % 3];
            const float* dR = rre[rr % 3];         // row ye+1
            const float* dI = rim[rr % 3];
            int xq = tid << 2;

            float4 c0q = *(const float4*)&cR[xq];   // wave-contiguous: conflict-free
            float4 c1q = *(const float4*)&cI[xq];
            float4 u0r = *(const float4*)&uR[xq];
            float4 u1r = *(const float4*)&uI[xq];
            float4 d0r = *(const float4*)&dR[xq];
            float4 d1r = *(const float4*)&dI[xq];
            float lf0 = cR[(xq - 1) & 1023], lf1 = cI[(xq - 1) & 1023];
            float rt0 = cR[(xq + 4) & 1023], rt1 = cI[(xq + 4) & 1023];

            float c0[4] = { c0q.x, c0q.y, c0q.z, c0q.w };
            float c1[4] = { c1q.x, c1q.y, c1q.z, c1q.w };
            float um0[4] = { u0r.x, u0r.y, u0r.z, u0r.w };
            float um1[4] = { u1r.x, u1r.y, u1r.z, u1r.w };
            float dp0[4] = { d0r.x, d0r.y, d0r.z, d0r.w };
            float dp1[4] = { d1r.x, d1r.y, d1r.z, d1r.w };
            float e0[6] = { lf0, c0[0], c0[1], c0[2], c0[3], rt0 };
            float e1[6] = { lf1, c1[0], c1[1], c1[2], c1[3], rt1 };

            size_t ro = (size_t)ye * WW + xq;
            float4 u0q = *(const float4*)(u0 + ro);
            float4 v0q = *(const float4*)(v0 + ro);
            float4 u1q = *(const float4*)(u1 + ro);
            float4 v1q = *(const float4*)(v1 + ro);
            float4 p0q = *(const float4*)(p0 + ro);
            float4 p1q = *(const float4*)(p1 + ro);

            float4 ou0, ov0, op0, ou1, ov1, op1;
            #pragma unroll
            for (int k = 0; k < 4; ++k) {
                ((float*)&ou0)[k] = ((float*)&u0q)[k] - 0.5f * (e0[k + 2] - e0[k]);
                ((float*)&ov0)[k] = ((float*)&v0q)[k] - 0.5f * (dp0[k] - um0[k]);
                ((float*)&op0)[k] = ((float*)&p0q)[k] + c0[k];
                ((float*)&ou1)[k] = ((float*)&u1q)[k] - 0.5f * (e1[k + 2] - e1[k]);
                ((float*)&ov1)[k] = ((float*)&v1q)[k] - 0.5f * (dp1[k] - um1[k]);
                ((float*)&op1)[k] = ((float*)&p1q)[k] + c1[k];
            }
            *(float4*)(o_u0 + ro) = ou0;
            *(float4*)(o_v0 + ro) = ov0;
            *(float4*)(o_p0 + ro) = op0;
            *(float4*)(o_u1 + ro) = ou1;
            *(float4*)(o_v1 + ro) = ov1;
            *(float4*)(o_p1 + ro) = op1;
        }
    }
}

extern "C" void kernel_launch(void* const* d_in, const int* in_sizes, int n_in,
                              void* d_out, int out_size, void* d_ws, size_t ws_size,
                              hipStream_t stream)
{
    const float* X    = (const float*)d_in[0];
    const float* beta = (const float*)d_in[1];
    const float* fu   = (const float*)d_in[2];
    const float* fv   = (const float*)d_in[3];
    float* out = (float*)d_out;
    float* ws  = (float*)d_ws;

    unsigned short* F1 = (unsigned short*)ws;     // 16M bf16 (32MB)
    float* UV  = ws + (size_t)BB * HW;            // 16M floats (64MB)
    float* Cbf = UV + (size_t)2 * BB * HW;        // 8M floats  (32MB)
    float* TWf = Cbf + (size_t)BB * HW;           // 2048 floats
    float* NRM = TWf + 2048;                      // 16 floats
    float2* Cb = (float2*)Cbf;
    float2* TW = (float2*)TWf;

    k_twid<<<4, 256, 0, stream>>>(TW, NRM);

    dim3 blk(256);

    k_diff3<<<2048, blk, 0, stream>>>(fu, fv, F1, NRM);
    k_star<<<dim3(HH, BB), blk, 0, stream>>>(X, beta, F1, NRM, UV);
    k_divfft<<<dim3(HH, BB / 2), blk, 0, stream>>>(UV, Cb, TW);
    k_colpass<<<dim3(WW / CT, 4), dim3(512), 0, stream>>>(Cb, TW);
    k_ifinal<<<dim3(HH / FBAND, BB / 2), blk, 0, stream>>>(Cb, UV, X, out, TW);
}

// Round 12
// 209.645 us; speedup vs baseline: 1.0123x; 1.0123x over previous
//
#include <hip/hip_runtime.h>

#define BB 8
#define HH 1024
#define WW 1024
#define HW (HH*WW)
#define PI_F 3.14159265358979323846f

static __device__ __forceinline__ void gload16(const float* g, float* l)
{
    __builtin_amdgcn_global_load_lds(
        (const __attribute__((address_space(1))) void*)g,
        (__attribute__((address_space(3))) void*)l,
        16, 0, 0);
}

// bf16 pack/unpack (round-to-nearest-even)
static __device__ __forceinline__ unsigned short f2bf(float f)
{
    unsigned u = __float_as_uint(f);
    return (unsigned short)((u + 0x7fffu + ((u >> 16) & 1u)) >> 16);
}
static __device__ __forceinline__ float bf2f(unsigned short h)
{
    return __uint_as_float(((unsigned)h) << 16);
}

// ---------------------------------------------------------------------------
// Twiddle table + NRM zeroing. Per-stage concatenated: stage with half-span
// len at offset (1024-2*len), len entries exp(-i*pi*j/len)
// ---------------------------------------------------------------------------
__global__ __launch_bounds__(256) void k_twid(float2* __restrict__ tw,
                                              float* __restrict__ nrm)
{
    int tid = blockIdx.x * 256 + threadIdx.x;   // 1024 threads
    if (tid < 16) nrm[tid] = 0.0f;
    for (int len = 512; len >= 1; len >>= 1) {
        int off = 1024 - 2 * len;
        float fac = -PI_F / (float)len;
        for (int j = tid; j < len; j += 1024) {
            float sn, cs;
            sincosf(fac * (float)j, &sn, &cs);
            tw[off + j] = make_float2(cs, sn);
        }
    }
}

// ---------------------------------------------------------------------------
// Fused 3x diffusion of f_u/f_v + L2 norm — full-width band register-march.
// Output bf16 (ushort): halves the F1 write. Norm accumulated in fp32.
// ---------------------------------------------------------------------------
#define RBAND 8
#define RAWROWS 14          // RBAND + 6

__global__ __launch_bounds__(256) void k_diff3(const float* __restrict__ su,
                                               const float* __restrict__ sv,
                                               unsigned short* __restrict__ dst,
                                               float* __restrict__ norms)
{
    __shared__ __align__(16) float A[RAWROWS * WW];   // 56 KB
    __shared__ float wsum[4];

    int bid = blockIdx.x;
    int work = (bid & 7) * 256 + (bid >> 3);
    int z = work >> 7;            // f*8+b, 0..15
    int band = work & 127;
    int f = z >> 3, b = z & 7;
    const float* s = ((f == 0) ? su : sv) + (size_t)b * HW;
    unsigned short* d = dst + (size_t)z * HW;
    int yb = band * RBAND;
    int tid = threadIdx.x;
    int w = tid >> 6, lane = tid & 63;

    for (int c = w; c < RAWROWS * 4; c += 4) {
        int row = c >> 2, seg = c & 3;
        const float* g = s + (size_t)((yb - 3 + row) & (HH - 1)) * WW
                           + (seg << 8) + (lane << 2);
        gload16(g, &A[(c << 8) + (lane << 2)]);
    }
    __syncthreads();

    const char* Ab = (const char*)A;
    int xq = tid << 4;
    int om = (xq - 16) & 4095;
    int op = (xq + 16) & 4095;

    float r[3][12];
    float i1[3][8];
    float i2[3][6];
    float sq = 0.0f;

    #pragma unroll
    for (int j = 0; j < RAWROWS; ++j) {
        {
            float4 a = *(const float4*)(Ab + j * 4096 + om);
            float4 bq = *(const float4*)(Ab + j * 4096 + xq);
            float4 cq = *(const float4*)(Ab + j * 4096 + op);
            float* rr = r[j % 3];
            rr[0] = a.x; rr[1] = a.y; rr[2] = a.z; rr[3] = a.w;
            rr[4] = bq.x; rr[5] = bq.y; rr[6] = bq.z; rr[7] = bq.w;
            rr[8] = cq.x; rr[9] = cq.y; rr[10] = cq.z; rr[11] = cq.w;
        }
        if (j >= 2) {
            const float* ru = r[(j - 2) % 3];
            const float* rc = r[(j - 1) % 3];
            const float* rd = r[j % 3];
            float* o = i1[(j - 1) % 3];
            #pragma unroll
            for (int k = 0; k < 8; ++k) {
                float c0 = rc[k + 2];
                o[k] = c0 + 0.1f * (rc[k + 1] + rc[k + 3] + ru[k + 2] + rd[k + 2] - 4.0f * c0);
            }
        }
        if (j >= 4) {
            const float* u = i1[(j - 3) % 3];
            const float* c = i1[(j - 2) % 3];
            const float* dd = i1[(j - 1) % 3];
            float* o = i2[(j - 2) % 3];
            #pragma unroll
            for (int k = 0; k < 6; ++k) {
                float c0 = c[k + 1];
                o[k] = c0 + 0.1f * (c[k] + c[k + 2] + u[k + 1] + dd[k + 1] - 4.0f * c0);
            }
        }
        if (j >= 6) {
            const float* u = i2[(j - 4) % 3];
            const float* c = i2[(j - 3) % 3];
            const float* dd = i2[(j - 2) % 3];
            float ov[4];
            #pragma unroll
            for (int k = 0; k < 4; ++k) {
                float c0 = c[k + 1];
                ov[k] = c0 + 0.1f * (c[k] + c[k + 2] + u[k + 1] + dd[k + 1] - 4.0f * c0);
            }
            ushort4 o16 = make_ushort4(f2bf(ov[0]), f2bf(ov[1]), f2bf(ov[2]), f2bf(ov[3]));
            *(ushort4*)(d + (size_t)(yb + j - 6) * WW + (tid << 2)) = o16;
            sq += ov[0] * ov[0] + ov[1] * ov[1] + ov[2] * ov[2] + ov[3] * ov[3];
        }
    }

    #pragma unroll
    for (int o = 32; o > 0; o >>= 1) sq += __shfl_down(sq, o, 64);
    if (lane == 0) wsum[w] = sq;
    __syncthreads();
    if (tid == 0)
        atomicAdd(&norms[z], wsum[0] + wsum[1] + wsum[2] + wsum[3]);
}

// ---------------------------------------------------------------------------
// Star velocities — quad-vectorized, block = one full row. F read as bf16.
// Row index XCD-swizzled for L2 halo locality.
// ---------------------------------------------------------------------------
__global__ __launch_bounds__(256) void k_star(const float* __restrict__ X,
                                              const float* __restrict__ beta,
                                              const unsigned short* __restrict__ F,
                                              const float* __restrict__ norms,
                                              float* __restrict__ UV)
{
    int b = blockIdx.y;
    int yx = blockIdx.x;
    int y = (yx & 7) * 128 + (yx >> 3);   // bijective XCD swizzle (1024 % 8 == 0)
    int tid = threadIdx.x;
    int lane = tid & 63;
    int xq = tid << 2;
    const float* u = X + (size_t)(b * 3 + 0) * HW;
    const float* v = X + (size_t)(b * 3 + 1) * HW;
    const float* p = X + (size_t)(b * 3 + 2) * HW;
    int yr = y * WW, ym = ((y - 1) & (HH - 1)) * WW, yp = ((y + 1) & (HH - 1)) * WW;

    float4 ucq = *(const float4*)(u + yr + xq);
    float4 uuq = *(const float4*)(u + ym + xq);
    float4 udq = *(const float4*)(u + yp + xq);
    float4 vcq = *(const float4*)(v + yr + xq);
    float4 vuq = *(const float4*)(v + ym + xq);
    float4 vdq = *(const float4*)(v + yp + xq);
    float4 pcq = *(const float4*)(p + yr + xq);
    float4 puq = *(const float4*)(p + ym + xq);
    float4 pdq = *(const float4*)(p + yp + xq);
    ushort4 fuq = *(const ushort4*)(F + (size_t)(0 * BB + b) * HW + yr + xq);
    ushort4 fvq = *(const ushort4*)(F + (size_t)(1 * BB + b) * HW + yr + xq);

    float ulf = __shfl_up(ucq.w, 1, 64), urt = __shfl_down(ucq.x, 1, 64);
    float vlf = __shfl_up(vcq.w, 1, 64), vrt = __shfl_down(vcq.x, 1, 64);
    float plf = __shfl_up(pcq.w, 1, 64), prt = __shfl_down(pcq.x, 1, 64);
    if (lane == 0)  { int xm = (xq - 1) & (WW - 1); ulf = u[yr + xm]; vlf = v[yr + xm]; plf = p[yr + xm]; }
    if (lane == 63) { int xp = (xq + 4) & (WW - 1); urt = u[yr + xp]; vrt = v[yr + xp]; prt = p[yr + xp]; }

    float ue[6] = { ulf, ucq.x, ucq.y, ucq.z, ucq.w, urt };
    float ve[6] = { vlf, vcq.x, vcq.y, vcq.z, vcq.w, vrt };
    float pe[6] = { plf, pcq.x, pcq.y, pcq.z, pcq.w, prt };
    float uu_[4] = { uuq.x, uuq.y, uuq.z, uuq.w };
    float ud_[4] = { udq.x, udq.y, udq.z, udq.w };
    float vu_[4] = { vuq.x, vuq.y, vuq.z, vuq.w };
    float vd_[4] = { vdq.x, vdq.y, vdq.z, vdq.w };
    float pu_[4] = { puq.x, puq.y, puq.z, puq.w };
    float pd_[4] = { pdq.x, pdq.y, pdq.z, pdq.w };
    float fu_[4] = { bf2f(fuq.x), bf2f(fuq.y), bf2f(fuq.z), bf2f(fuq.w) };
    float fv_[4] = { bf2f(fvq.x), bf2f(fvq.y), bf2f(fvq.z), bf2f(fvq.w) };

    float sb = sqrtf(beta[b]);
    float inu = 1.0f / fmaxf(sqrtf(norms[b]), 1e-12f);
    float inv = 1.0f / fmaxf(sqrtf(norms[BB + b]), 1e-12f);

    float4 un4, vn4;
    float* unp = (float*)&un4;
    float* vnp = (float*)&vn4;
    #pragma unroll
    for (int k = 0; k < 4; ++k) {
        float ucc = ue[k + 1], vcc = ve[k + 1];
        float adv_u = ucc * (0.5f * (ue[k + 2] - ue[k])) + vcc * (0.5f * (ud_[k] - uu_[k]));
        float adv_v = ucc * (0.5f * (ve[k + 2] - ve[k])) + vcc * (0.5f * (vd_[k] - vu_[k]));
        float lap_u = ue[k] + ue[k + 2] + uu_[k] + ud_[k] - 4.0f * ucc;
        float lap_v = ve[k] + ve[k + 2] + vu_[k] + vd_[k] - 4.0f * vcc;
        float dpdx = 0.5f * (pe[k + 2] - pe[k]);
        float dpdy = 0.5f * (pd_[k] - pu_[k]);
        unp[k] = ucc + 0.01f * (-adv_u + 0.01f * lap_u - dpdx) + sb * fu_[k] * inu;
        vnp[k] = vcc + 0.01f * (-adv_v + 0.01f * lap_v - dpdy) + sb * fv_[k] * inv;
    }

    *(float4*)(UV + (size_t)(0 * BB + b) * HW + yr + xq) = un4;
    *(float4*)(UV + (size_t)(1 * BB + b) * HW + yr + xq) = vn4;
}

// ---------------------------------------------------------------------------
// float2-based FFT helpers (length 1024, LDS, 256 threads, block-wide)
// ---------------------------------------------------------------------------
static __device__ __forceinline__ void fft_dif2(float2* d, const float2* tw)
{
    int t = threadIdx.x;
    for (int s = 9; s >= 0; --s) {
        int len = 1 << s;
        int off = 1024 - 2 * len;
        __syncthreads();
        #pragma unroll
        for (int k = 0; k < 2; ++k) {
            int bt = t + (k << 8);
            int j = bt & (len - 1);
            int i = ((bt >> s) << (s + 1)) | j;
            float2 u = d[i], v = d[i + len], w = tw[off + j];
            d[i] = make_float2(u.x + v.x, u.y + v.y);
            float dr = u.x - v.x, di = u.y - v.y;
            d[i + len] = make_float2(dr * w.x - di * w.y, dr * w.y + di * w.x);
        }
    }
}

static __device__ __forceinline__ void fft_dit_inv2(float2* d, const float2* tw)
{
    int t = threadIdx.x;
    for (int s = 0; s <= 9; ++s) {
        int len = 1 << s;
        int off = 1024 - 2 * len;
        __syncthreads();
        #pragma unroll
        for (int k = 0; k < 2; ++k) {
            int bt = t + (k << 8);
            int j = bt & (len - 1);
            int i = ((bt >> s) << (s + 1)) | j;
            float2 u = d[i], v = d[i + len], w = tw[off + j];   // conj(w)
            float tr = v.x * w.x + v.y * w.y;
            float ti = v.y * w.x - v.x * w.y;
            d[i] = make_float2(u.x + tr, u.y + ti);
            d[i + len] = make_float2(u.x - tr, u.y - ti);
        }
    }
}

// ---------------------------------------------------------------------------
// Fused divergence + forward row FFT. Block = (row y, pair q). Row swizzled.
// ---------------------------------------------------------------------------
__global__ __launch_bounds__(256) void k_divfft(const float* __restrict__ UV,
                                                float2* __restrict__ dst,
                                                const float2* __restrict__ tw)
{
    __shared__ __align__(16) float2 data[1024];
    __shared__ __align__(16) float2 twl[1024];
    __shared__ __align__(16) float us0[1024], us1[1024];
    int yx = blockIdx.x, q = blockIdx.y;
    int y = (yx & 7) * 128 + (yx >> 3);   // XCD swizzle
    int b0 = 2 * q, b1 = 2 * q + 1;
    int tid = threadIdx.x, w = tid >> 6, lane = tid & 63;
    int yr = y * WW, ym = ((y - 1) & (HH - 1)) * WW, yp = ((y + 1) & (HH - 1)) * WW;
    const float* u0 = UV + (size_t)b0 * HW;
    const float* v0 = UV + (size_t)(BB + b0) * HW;
    const float* u1 = UV + (size_t)b1 * HW;
    const float* v1 = UV + (size_t)(BB + b1) * HW;

    gload16(u0 + yr + (w << 8) + (lane << 2), &us0[(w << 8) + (lane << 2)]);
    gload16(u1 + yr + (w << 8) + (lane << 2), &us1[(w << 8) + (lane << 2)]);

    for (int j = tid; j < 1024; j += 256) twl[j] = tw[j];

    int xq = tid << 2;
    float4 v0u = *(const float4*)(v0 + ym + xq);
    float4 v0d = *(const float4*)(v0 + yp + xq);
    float4 v1u = *(const float4*)(v1 + ym + xq);
    float4 v1d = *(const float4*)(v1 + yp + xq);
    __syncthreads();   // drains DMA (vmcnt) + twl

    float4 c0 = *(const float4*)&us0[xq];
    float4 c1 = *(const float4*)&us1[xq];
    float lf0 = us0[(xq - 1) & 1023], rt0 = us0[(xq + 4) & 1023];
    float lf1 = us1[(xq - 1) & 1023], rt1 = us1[(xq + 4) & 1023];
    float u0e[6] = { lf0, c0.x, c0.y, c0.z, c0.w, rt0 };
    float u1e[6] = { lf1, c1.x, c1.y, c1.z, c1.w, rt1 };
    float v0u_[4] = { v0u.x, v0u.y, v0u.z, v0u.w };
    float v0d_[4] = { v0d.x, v0d.y, v0d.z, v0d.w };
    float v1u_[4] = { v1u.x, v1u.y, v1u.z, v1u.w };
    float v1d_[4] = { v1d.x, v1d.y, v1d.z, v1d.w };
    #pragma unroll
    for (int k = 0; k < 4; ++k) {
        float d0 = 0.5f * (u0e[k + 2] - u0e[k]) + 0.5f * (v0d_[k] - v0u_[k]);
        float d1 = 0.5f * (u1e[k + 2] - u1e[k]) + 0.5f * (v1d_[k] - v1u_[k]);
        data[xq + k] = make_float2(d0, d1);
    }

    fft_dif2(data, twl);
    __syncthreads();
    size_t base = (size_t)((q << 10) + y) << 10;
    float4* dst4 = (float4*)(dst + base);
    float4* dat4 = (float4*)data;
    dst4[2 * tid] = dat4[2 * tid];
    dst4[2 * tid + 1] = dat4[2 * tid + 1];
}

// ---------------------------------------------------------------------------
// Fused column pass: CT=8 columns/block, 512 threads (8 waves), 2 blocks/CU.
// Per-wave 1024-pt FFT, wave-local; Poisson scale; inverse FFT; in place.
// ---------------------------------------------------------------------------
#define CT 8
#define CSTR 1026

__global__ __launch_bounds__(512) void k_colpass(float2* __restrict__ spec,
                                                 const float2* __restrict__ tw)
{
    __shared__ __align__(16) float2 colbuf[CT * CSTR];   // 65664 B
    __shared__ __align__(16) float2 twl[1024];           // 8192 B
    int tile = blockIdx.x, q = blockIdx.y;
    int i0 = tile * CT;
    int tid = threadIdx.x, lane = tid & 63, w = tid >> 6;
    size_t qb = (size_t)q * HW;

    twl[tid] = tw[tid];
    twl[tid + 512] = tw[tid + 512];

    float2* g = spec + qb;
    #pragma unroll 4
    for (int pass = 0; pass < 16; ++pass) {
        int n = (pass << 9) + tid;
        int r = n >> 3, c = n & 7;
        colbuf[c * CSTR + r] = g[(size_t)r * 1024 + i0 + c];
    }
    __syncthreads();

    // --- per-wave column FFT (column i0+w) ---------------------------------
    float2* d = colbuf + w * CSTR;
    int i = i0 + w;
    int kx = __brev((unsigned)i) >> 22;
    int fx = (kx < 512) ? kx : kx - 1024;
    float fx2 = (float)(fx * fx);

    for (int s = 9; s >= 0; --s) {
        int len = 1 << s, off = 1024 - 2 * len;
        asm volatile("s_waitcnt lgkmcnt(0)" ::: "memory");
        __builtin_amdgcn_sched_barrier(0);
        #pragma unroll
        for (int k = 0; k < 8; ++k) {
            int bt = lane + (k << 6);
            int j = bt & (len - 1);
            int ii = ((bt >> s) << (s + 1)) | j;
            float2 u = d[ii], v = d[ii + len], wv = twl[off + j];
            d[ii] = make_float2(u.x + v.x, u.y + v.y);
            float dr = u.x - v.x, di = u.y - v.y;
            d[ii + len] = make_float2(dr * wv.x - di * wv.y, dr * wv.y + di * wv.x);
        }
    }
    asm volatile("s_waitcnt lgkmcnt(0)" ::: "memory");
    __builtin_amdgcn_sched_barrier(0);
    const float cc = -1.0f / (4.0f * PI_F * PI_F * 1024.0f * 1024.0f); // incl. 1/(H*W)
    #pragma unroll
    for (int k = 0; k < 16; ++k) {
        int kk = lane + (k << 6);
        int ky = __brev((unsigned)kk) >> 22;
        int fy = (ky < 512) ? ky : ky - 1024;
        float k2 = fx2 + (float)(fy * fy);
        float s = (k2 > 0.0f) ? (cc / k2) : 0.0f;   // DC zeroed
        float2 v = d[kk];
        d[kk] = make_float2(v.x * s, v.y * s);
    }
    for (int s = 0; s <= 9; ++s) {
        int len = 1 << s, off = 1024 - 2 * len;
        asm volatile("s_waitcnt lgkmcnt(0)" ::: "memory");
        __builtin_amdgcn_sched_barrier(0);
        #pragma unroll
        for (int k = 0; k < 8; ++k) {
            int bt = lane + (k << 6);
            int j = bt & (len - 1);
            int ii = ((bt >> s) << (s + 1)) | j;
            float2 u = d[ii], v = d[ii + len], wv = twl[off + j];   // conj(w)
            float tr = v.x * wv.x + v.y * wv.y;
            float ti = v.y * wv.x - v.x * wv.y;
            d[ii] = make_float2(u.x + tr, u.y + ti);
            d[ii + len] = make_float2(u.x - tr, u.y - ti);
        }
    }
    asm volatile("s_waitcnt lgkmcnt(0)" ::: "memory");
    __builtin_amdgcn_sched_barrier(0);
    __syncthreads();

    #pragma unroll 4
    for (int pass = 0; pass < 16; ++pass) {
        int n = (pass << 9) + tid;
        int r = n >> 3, c = n & 7;
        g[(size_t)r * 1024 + i0 + c] = colbuf[c * CSTR + r];
    }
}

// ---------------------------------------------------------------------------
// Fused inverse row FFT + final projection. Round-9 structure (float2 ring,
// DMA spectrum load, float4 emit) with FBAND 4->8: halo IFFT overhead drops
// from 1.5x to 1.25x, spec re-fetch 48->40 MB. Grid 128x4 = 512 blocks.
// ---------------------------------------------------------------------------
#define FBAND 8

__global__ __launch_bounds__(256) void k_ifinal(const float2* __restrict__ spec,
                                                const float* __restrict__ UV,
                                                const float* __restrict__ X,
                                                float* __restrict__ out,
                                                const float2* __restrict__ tw)
{
    __shared__ __align__(16) float2 ring[3][1024];   // 24 KB
    __shared__ __align__(16) float2 twl[1024];       // 8 KB
    int bx = blockIdx.x, q = blockIdx.y;
    int band = (bx & 7) * 16 + (bx >> 3);   // XCD swizzle (128 % 8 == 0)
    int b0 = 2 * q, b1 = 2 * q + 1;
    int y0 = band * FBAND;
    int tid = threadIdx.x, w = tid >> 6, lane = tid & 63;

    for (int j = tid; j < 1024; j += 256) twl[j] = tw[j];

    size_t sbase = (size_t)q * HW;
    const float* u0 = UV + (size_t)(0 * BB + b0) * HW;
    const float* v0 = UV + (size_t)(BB + b0) * HW;
    const float* u1 = UV + (size_t)(0 * BB + b1) * HW;
    const float* v1 = UV + (size_t)(BB + b1) * HW;
    const float* p0 = X + (size_t)(b0 * 3 + 2) * HW;
    const float* p1 = X + (size_t)(b1 * 3 + 2) * HW;
    float* o_u0 = out + (size_t)(b0 * 3 + 0) * HW;
    float* o_v0 = out + (size_t)(b0 * 3 + 1) * HW;
    float* o_p0 = out + (size_t)(b0 * 3 + 2) * HW;
    float* o_u1 = out + (size_t)(b1 * 3 + 0) * HW;
    float* o_v1 = out + (size_t)(b1 * 3 + 1) * HW;
    float* o_p1 = out + (size_t)(b1 * 3 + 2) * HW;

    for (int rr = 0; rr < FBAND + 2; ++rr) {
        int yg = (y0 - 1 + rr) & (HH - 1);
        float2* slot = ring[rr % 3];

        __syncthreads();   // prior emit readers done before overwriting oldest slot
        const float* g = (const float*)(spec + sbase + (size_t)yg * 1024);
        for (int cch = w; cch < 8; cch += 4)
            gload16(g + (cch << 8) + (lane << 2), ((float*)slot) + (cch << 8) + (lane << 2));

        fft_dit_inv2(slot, twl);   // internal stage barriers drain DMA first
        __syncthreads();           // slot complete

        if (rr >= 2) {
            int ye = y0 + rr - 2;
            const float2* pcn = ring[(rr - 1) % 3];   // row ye
            const float2* ppm = ring[(rr - 2) % 3];   // row ye-1
            const float2* ppp = ring[rr % 3];         // row ye+1
            int xq = tid << 2;

            float4 cA = *(const float4*)&pcn[xq];
            float4 cB = *(const float4*)&pcn[xq + 2];
            float4 uA = *(const float4*)&ppm[xq];
            float4 uB = *(const float4*)&ppm[xq + 2];
            float4 dA = *(const float4*)&ppp[xq];
            float4 dB = *(const float4*)&ppp[xq + 2];
            float2 lf = pcn[(xq - 1) & 1023];
            float2 rt = pcn[(xq + 4) & 1023];

            float c0[4] = { cA.x, cA.z, cB.x, cB.z }, c1[4] = { cA.y, cA.w, cB.y, cB.w };
            float um0[4] = { uA.x, uA.z, uB.x, uB.z }, um1[4] = { uA.y, uA.w, uB.y, uB.w };
            float dp0[4] = { dA.x, dA.z, dB.x, dB.z }, dp1[4] = { dA.y, dA.w, dB.y, dB.w };
            float e0[6] = { lf.x, c0[0], c0[1], c0[2], c0[3], rt.x };
            float e1[6] = { lf.y, c1[0], c1[1], c1[2], c1[3], rt.y };

            size_t ro = (size_t)ye * WW + xq;
            float4 u0q = *(const float4*)(u0 + ro);
            float4 v0q = *(const float4*)(v0 + ro);
            float4 u1q = *(const float4*)(u1 + ro);
            float4 v1q = *(const float4*)(v1 + ro);
            float4 p0q = *(const float4*)(p0 + ro);
            float4 p1q = *(const float4*)(p1 + ro);

            float4 ou0, ov0, op0, ou1, ov1, op1;
            #pragma unroll
            for (int k = 0; k < 4; ++k) {
                ((float*)&ou0)[k] = ((float*)&u0q)[k] - 0.5f * (e0[k + 2] - e0[k]);
                ((float*)&ov0)[k] = ((float*)&v0q)[k] - 0.5f * (dp0[k] - um0[k]);
                ((float*)&op0)[k] = ((float*)&p0q)[k] + c0[k];
                ((float*)&ou1)[k] = ((float*)&u1q)[k] - 0.5f * (e1[k + 2] - e1[k]);
                ((float*)&ov1)[k] = ((float*)&v1q)[k] - 0.5f * (dp1[k] - um1[k]);
                ((float*)&op1)[k] = ((float*)&p1q)[k] + c1[k];
            }
            *(float4*)(o_u0 + ro) = ou0;
            *(float4*)(o_v0 + ro) = ov0;
            *(float4*)(o_p0 + ro) = op0;
            *(float4*)(o_u1 + ro) = ou1;
            *(float4*)(o_v1 + ro) = ov1;
            *(float4*)(o_p1 + ro) = op1;
        }
    }
}

extern "C" void kernel_launch(void* const* d_in, const int* in_sizes, int n_in,
                              void* d_out, int out_size, void* d_ws, size_t ws_size,
                              hipStream_t stream)
{
    const float* X    = (const float*)d_in[0];
    const float* beta = (const float*)d_in[1];
    const float* fu   = (const float*)d_in[2];
    const float* fv   = (const float*)d_in[3];
    float* out = (float*)d_out;
    float* ws  = (float*)d_ws;

    unsigned short* F1 = (unsigned short*)ws;     // 16M bf16 (32MB)
    float* UV  = ws + (size_t)BB * HW;            // 16M floats (64MB)
    float* Cbf = UV + (size_t)2 * BB * HW;        // 8M floats  (32MB)
    float* TWf = Cbf + (size_t)BB * HW;           // 2048 floats
    float* NRM = TWf + 2048;                      // 16 floats
    float2* Cb = (float2*)Cbf;
    float2* TW = (float2*)TWf;

    k_twid<<<4, 256, 0, stream>>>(TW, NRM);

    dim3 blk(256);

    k_diff3<<<2048, blk, 0, stream>>>(fu, fv, F1, NRM);
    k_star<<<dim3(HH, BB), blk, 0, stream>>>(X, beta, F1, NRM, UV);
    k_divfft<<<dim3(HH, BB / 2), blk, 0, stream>>>(UV, Cb, TW);
    k_colpass<<<dim3(WW / CT, 4), dim3(512), 0, stream>>>(Cb, TW);
    k_ifinal<<<dim3(HH / FBAND, BB / 2), blk, 0, stream>>>(Cb, UV, X, out, TW);
}

// Round 13
// 205.847 us; speedup vs baseline: 1.0309x; 1.0184x over previous
//
#include <hip/hip_runtime.h>

#define BB 8
#define HH 1024
#define WW 1024
#define HW (HH*WW)
#define PI_F 3.14159265358979323846f

static __device__ __forceinline__ void gload16(const float* g, float* l)
{
    __builtin_amdgcn_global_load_lds(
        (const __attribute__((address_space(1))) void*)g,
        (__attribute__((address_space(3))) void*)l,
        16, 0, 0);
}

// bf16 pack/unpack (round-to-nearest-even)
static __device__ __forceinline__ unsigned short f2bf(float f)
{
    unsigned u = __float_as_uint(f);
    return (unsigned short)((u + 0x7fffu + ((u >> 16) & 1u)) >> 16);
}
static __device__ __forceinline__ float bf2f(unsigned short h)
{
    return __uint_as_float(((unsigned)h) << 16);
}

// ---------------------------------------------------------------------------
// Twiddle table + NRM zeroing. Per-stage concatenated: stage with half-span
// len at offset (1024-2*len), len entries exp(-i*pi*j/len)
// ---------------------------------------------------------------------------
__global__ __launch_bounds__(256) void k_twid(float2* __restrict__ tw,
                                              float* __restrict__ nrm)
{
    int tid = blockIdx.x * 256 + threadIdx.x;   // 1024 threads
    if (tid < 16) nrm[tid] = 0.0f;
    for (int len = 512; len >= 1; len >>= 1) {
        int off = 1024 - 2 * len;
        float fac = -PI_F / (float)len;
        for (int j = tid; j < len; j += 1024) {
            float sn, cs;
            sincosf(fac * (float)j, &sn, &cs);
            tw[off + j] = make_float2(cs, sn);
        }
    }
}

// ---------------------------------------------------------------------------
// Fused 3x diffusion of f_u/f_v + L2 norm — full-width band register-march.
// Output bf16 (ushort): halves the F1 write. Norm accumulated in fp32.
// ---------------------------------------------------------------------------
#define RBAND 8
#define RAWROWS 14          // RBAND + 6

__global__ __launch_bounds__(256) void k_diff3(const float* __restrict__ su,
                                               const float* __restrict__ sv,
                                               unsigned short* __restrict__ dst,
                                               float* __restrict__ norms)
{
    __shared__ __align__(16) float A[RAWROWS * WW];   // 56 KB
    __shared__ float wsum[4];

    int bid = blockIdx.x;
    int work = (bid & 7) * 256 + (bid >> 3);
    int z = work >> 7;            // f*8+b, 0..15
    int band = work & 127;
    int f = z >> 3, b = z & 7;
    const float* s = ((f == 0) ? su : sv) + (size_t)b * HW;
    unsigned short* d = dst + (size_t)z * HW;
    int yb = band * RBAND;
    int tid = threadIdx.x;
    int w = tid >> 6, lane = tid & 63;

    for (int c = w; c < RAWROWS * 4; c += 4) {
        int row = c >> 2, seg = c & 3;
        const float* g = s + (size_t)((yb - 3 + row) & (HH - 1)) * WW
                           + (seg << 8) + (lane << 2);
        gload16(g, &A[(c << 8) + (lane << 2)]);
    }
    __syncthreads();

    const char* Ab = (const char*)A;
    int xq = tid << 4;
    int om = (xq - 16) & 4095;
    int op = (xq + 16) & 4095;

    float r[3][12];
    float i1[3][8];
    float i2[3][6];
    float sq = 0.0f;

    #pragma unroll
    for (int j = 0; j < RAWROWS; ++j) {
        {
            float4 a = *(const float4*)(Ab + j * 4096 + om);
            float4 bq = *(const float4*)(Ab + j * 4096 + xq);
            float4 cq = *(const float4*)(Ab + j * 4096 + op);
            float* rr = r[j % 3];
            rr[0] = a.x; rr[1] = a.y; rr[2] = a.z; rr[3] = a.w;
            rr[4] = bq.x; rr[5] = bq.y; rr[6] = bq.z; rr[7] = bq.w;
            rr[8] = cq.x; rr[9] = cq.y; rr[10] = cq.z; rr[11] = cq.w;
        }
        if (j >= 2) {
            const float* ru = r[(j - 2) % 3];
            const float* rc = r[(j - 1) % 3];
            const float* rd = r[j % 3];
            float* o = i1[(j - 1) % 3];
            #pragma unroll
            for (int k = 0; k < 8; ++k) {
                float c0 = rc[k + 2];
                o[k] = c0 + 0.1f * (rc[k + 1] + rc[k + 3] + ru[k + 2] + rd[k + 2] - 4.0f * c0);
            }
        }
        if (j >= 4) {
            const float* u = i1[(j - 3) % 3];
            const float* c = i1[(j - 2) % 3];
            const float* dd = i1[(j - 1) % 3];
            float* o = i2[(j - 2) % 3];
            #pragma unroll
            for (int k = 0; k < 6; ++k) {
                float c0 = c[k + 1];
                o[k] = c0 + 0.1f * (c[k] + c[k + 2] + u[k + 1] + dd[k + 1] - 4.0f * c0);
            }
        }
        if (j >= 6) {
            const float* u = i2[(j - 4) % 3];
            const float* c = i2[(j - 3) % 3];
            const float* dd = i2[(j - 2) % 3];
            float ov[4];
            #pragma unroll
            for (int k = 0; k < 4; ++k) {
                float c0 = c[k + 1];
                ov[k] = c0 + 0.1f * (c[k] + c[k + 2] + u[k + 1] + dd[k + 1] - 4.0f * c0);
            }
            ushort4 o16 = make_ushort4(f2bf(ov[0]), f2bf(ov[1]), f2bf(ov[2]), f2bf(ov[3]));
            *(ushort4*)(d + (size_t)(yb + j - 6) * WW + (tid << 2)) = o16;
            sq += ov[0] * ov[0] + ov[1] * ov[1] + ov[2] * ov[2] + ov[3] * ov[3];
        }
    }

    #pragma unroll
    for (int o = 32; o > 0; o >>= 1) sq += __shfl_down(sq, o, 64);
    if (lane == 0) wsum[w] = sq;
    __syncthreads();
    if (tid == 0)
        atomicAdd(&norms[z], wsum[0] + wsum[1] + wsum[2] + wsum[3]);
}

// ---------------------------------------------------------------------------
// Star velocities — quad-vectorized, block = one full row. F read as bf16.
// Row index XCD-swizzled for L2 halo locality.
// ---------------------------------------------------------------------------
__global__ __launch_bounds__(256) void k_star(const float* __restrict__ X,
                                              const float* __restrict__ beta,
                                              const unsigned short* __restrict__ F,
                                              const float* __restrict__ norms,
                                              float* __restrict__ UV)
{
    int b = blockIdx.y;
    int yx = blockIdx.x;
    int y = (yx & 7) * 128 + (yx >> 3);   // bijective XCD swizzle (1024 % 8 == 0)
    int tid = threadIdx.x;
    int lane = tid & 63;
    int xq = tid << 2;
    const float* u = X + (size_t)(b * 3 + 0) * HW;
    const float* v = X + (size_t)(b * 3 + 1) * HW;
    const float* p = X + (size_t)(b * 3 + 2) * HW;
    int yr = y * WW, ym = ((y - 1) & (HH - 1)) * WW, yp = ((y + 1) & (HH - 1)) * WW;

    float4 ucq = *(const float4*)(u + yr + xq);
    float4 uuq = *(const float4*)(u + ym + xq);
    float4 udq = *(const float4*)(u + yp + xq);
    float4 vcq = *(const float4*)(v + yr + xq);
    float4 vuq = *(const float4*)(v + ym + xq);
    float4 vdq = *(const float4*)(v + yp + xq);
    float4 pcq = *(const float4*)(p + yr + xq);
    float4 puq = *(const float4*)(p + ym + xq);
    float4 pdq = *(const float4*)(p + yp + xq);
    ushort4 fuq = *(const ushort4*)(F + (size_t)(0 * BB + b) * HW + yr + xq);
    ushort4 fvq = *(const ushort4*)(F + (size_t)(1 * BB + b) * HW + yr + xq);

    float ulf = __shfl_up(ucq.w, 1, 64), urt = __shfl_down(ucq.x, 1, 64);
    float vlf = __shfl_up(vcq.w, 1, 64), vrt = __shfl_down(vcq.x, 1, 64);
    float plf = __shfl_up(pcq.w, 1, 64), prt = __shfl_down(pcq.x, 1, 64);
    if (lane == 0)  { int xm = (xq - 1) & (WW - 1); ulf = u[yr + xm]; vlf = v[yr + xm]; plf = p[yr + xm]; }
    if (lane == 63) { int xp = (xq + 4) & (WW - 1); urt = u[yr + xp]; vrt = v[yr + xp]; prt = p[yr + xp]; }

    float ue[6] = { ulf, ucq.x, ucq.y, ucq.z, ucq.w, urt };
    float ve[6] = { vlf, vcq.x, vcq.y, vcq.z, vcq.w, vrt };
    float pe[6] = { plf, pcq.x, pcq.y, pcq.z, pcq.w, prt };
    float uu_[4] = { uuq.x, uuq.y, uuq.z, uuq.w };
    float ud_[4] = { udq.x, udq.y, udq.z, udq.w };
    float vu_[4] = { vuq.x, vuq.y, vuq.z, vuq.w };
    float vd_[4] = { vdq.x, vdq.y, vdq.z, vdq.w };
    float pu_[4] = { puq.x, puq.y, puq.z, puq.w };
    float pd_[4] = { pdq.x, pdq.y, pdq.z, pdq.w };
    float fu_[4] = { bf2f(fuq.x), bf2f(fuq.y), bf2f(fuq.z), bf2f(fuq.w) };
    float fv_[4] = { bf2f(fvq.x), bf2f(fvq.y), bf2f(fvq.z), bf2f(fvq.w) };

    float sb = sqrtf(beta[b]);
    float inu = 1.0f / fmaxf(sqrtf(norms[b]), 1e-12f);
    float inv = 1.0f / fmaxf(sqrtf(norms[BB + b]), 1e-12f);

    float4 un4, vn4;
    float* unp = (float*)&un4;
    float* vnp = (float*)&vn4;
    #pragma unroll
    for (int k = 0; k < 4; ++k) {
        float ucc = ue[k + 1], vcc = ve[k + 1];
        float adv_u = ucc * (0.5f * (ue[k + 2] - ue[k])) + vcc * (0.5f * (ud_[k] - uu_[k]));
        float adv_v = ucc * (0.5f * (ve[k + 2] - ve[k])) + vcc * (0.5f * (vd_[k] - vu_[k]));
        float lap_u = ue[k] + ue[k + 2] + uu_[k] + ud_[k] - 4.0f * ucc;
        float lap_v = ve[k] + ve[k + 2] + vu_[k] + vd_[k] - 4.0f * vcc;
        float dpdx = 0.5f * (pe[k + 2] - pe[k]);
        float dpdy = 0.5f * (pd_[k] - pu_[k]);
        unp[k] = ucc + 0.01f * (-adv_u + 0.01f * lap_u - dpdx) + sb * fu_[k] * inu;
        vnp[k] = vcc + 0.01f * (-adv_v + 0.01f * lap_v - dpdy) + sb * fv_[k] * inv;
    }

    *(float4*)(UV + (size_t)(0 * BB + b) * HW + yr + xq) = un4;
    *(float4*)(UV + (size_t)(1 * BB + b) * HW + yr + xq) = vn4;
}

// ---------------------------------------------------------------------------
// float2-based FFT helpers (length 1024, LDS, 256 threads, block-wide)
// ---------------------------------------------------------------------------
static __device__ __forceinline__ void fft_dif2(float2* d, const float2* tw)
{
    int t = threadIdx.x;
    for (int s = 9; s >= 0; --s) {
        int len = 1 << s;
        int off = 1024 - 2 * len;
        __syncthreads();
        #pragma unroll
        for (int k = 0; k < 2; ++k) {
            int bt = t + (k << 8);
            int j = bt & (len - 1);
            int i = ((bt >> s) << (s + 1)) | j;
            float2 u = d[i], v = d[i + len], w = tw[off + j];
            d[i] = make_float2(u.x + v.x, u.y + v.y);
            float dr = u.x - v.x, di = u.y - v.y;
            d[i + len] = make_float2(dr * w.x - di * w.y, dr * w.y + di * w.x);
        }
    }
}

static __device__ __forceinline__ void fft_dit_inv2(float2* d, const float2* tw)
{
    int t = threadIdx.x;
    for (int s = 0; s <= 9; ++s) {
        int len = 1 << s;
        int off = 1024 - 2 * len;
        __syncthreads();
        #pragma unroll
        for (int k = 0; k < 2; ++k) {
            int bt = t + (k << 8);
            int j = bt & (len - 1);
            int i = ((bt >> s) << (s + 1)) | j;
            float2 u = d[i], v = d[i + len], w = tw[off + j];   // conj(w)
            float tr = v.x * w.x + v.y * w.y;
            float ti = v.y * w.x - v.x * w.y;
            d[i] = make_float2(u.x + tr, u.y + ti);
            d[i + len] = make_float2(u.x - tr, u.y - ti);
        }
    }
}

// ---------------------------------------------------------------------------
// Fused divergence + forward row FFT. Block = (row y, pair q). Row swizzled.
// ---------------------------------------------------------------------------
__global__ __launch_bounds__(256) void k_divfft(const float* __restrict__ UV,
                                                float2* __restrict__ dst,
                                                const float2* __restrict__ tw)
{
    __shared__ __align__(16) float2 data[1024];
    __shared__ __align__(16) float2 twl[1024];
    __shared__ __align__(16) float us0[1024], us1[1024];
    int yx = blockIdx.x, q = blockIdx.y;
    int y = (yx & 7) * 128 + (yx >> 3);   // XCD swizzle
    int b0 = 2 * q, b1 = 2 * q + 1;
    int tid = threadIdx.x, w = tid >> 6, lane = tid & 63;
    int yr = y * WW, ym = ((y - 1) & (HH - 1)) * WW, yp = ((y + 1) & (HH - 1)) * WW;
    const float* u0 = UV + (size_t)b0 * HW;
    const float* v0 = UV + (size_t)(BB + b0) * HW;
    const float* u1 = UV + (size_t)b1 * HW;
    const float* v1 = UV + (size_t)(BB + b1) * HW;

    gload16(u0 + yr + (w << 8) + (lane << 2), &us0[(w << 8) + (lane << 2)]);
    gload16(u1 + yr + (w << 8) + (lane << 2), &us1[(w << 8) + (lane << 2)]);

    for (int j = tid; j < 1024; j += 256) twl[j] = tw[j];

    int xq = tid << 2;
    float4 v0u = *(const float4*)(v0 + ym + xq);
    float4 v0d = *(const float4*)(v0 + yp + xq);
    float4 v1u = *(const float4*)(v1 + ym + xq);
    float4 v1d = *(const float4*)(v1 + yp + xq);
    __syncthreads();   // drains DMA (vmcnt) + twl

    float4 c0 = *(const float4*)&us0[xq];
    float4 c1 = *(const float4*)&us1[xq];
    float lf0 = us0[(xq - 1) & 1023], rt0 = us0[(xq + 4) & 1023];
    float lf1 = us1[(xq - 1) & 1023], rt1 = us1[(xq + 4) & 1023];
    float u0e[6] = { lf0, c0.x, c0.y, c0.z, c0.w, rt0 };
    float u1e[6] = { lf1, c1.x, c1.y, c1.z, c1.w, rt1 };
    float v0u_[4] = { v0u.x, v0u.y, v0u.z, v0u.w };
    float v0d_[4] = { v0d.x, v0d.y, v0d.z, v0d.w };
    float v1u_[4] = { v1u.x, v1u.y, v1u.z, v1u.w };
    float v1d_[4] = { v1d.x, v1d.y, v1d.z, v1d.w };
    #pragma unroll
    for (int k = 0; k < 4; ++k) {
        float d0 = 0.5f * (u0e[k + 2] - u0e[k]) + 0.5f * (v0d_[k] - v0u_[k]);
        float d1 = 0.5f * (u1e[k + 2] - u1e[k]) + 0.5f * (v1d_[k] - v1u_[k]);
        data[xq + k] = make_float2(d0, d1);
    }

    fft_dif2(data, twl);
    __syncthreads();
    size_t base = (size_t)((q << 10) + y) << 10;
    float4* dst4 = (float4*)(dst + base);
    float4* dat4 = (float4*)data;
    dst4[2 * tid] = dat4[2 * tid];
    dst4[2 * tid + 1] = dat4[2 * tid + 1];
}

// ---------------------------------------------------------------------------
// Fused column pass: CT=8 columns/block, 512 threads (8 waves), 2 blocks/CU.
// Per-wave 1024-pt FFT, wave-local; Poisson scale; inverse FFT; in place.
// ---------------------------------------------------------------------------
#define CT 8
#define CSTR 1026

__global__ __launch_bounds__(512) void k_colpass(float2* __restrict__ spec,
                                                 const float2* __restrict__ tw)
{
    __shared__ __align__(16) float2 colbuf[CT * CSTR];   // 65664 B
    __shared__ __align__(16) float2 twl[1024];           // 8192 B
    int tile = blockIdx.x, q = blockIdx.y;
    int i0 = tile * CT;
    int tid = threadIdx.x, lane = tid & 63, w = tid >> 6;
    size_t qb = (size_t)q * HW;

    twl[tid] = tw[tid];
    twl[tid + 512] = tw[tid + 512];

    float2* g = spec + qb;
    #pragma unroll 4
    for (int pass = 0; pass < 16; ++pass) {
        int n = (pass << 9) + tid;
        int r = n >> 3, c = n & 7;
        colbuf[c * CSTR + r] = g[(size_t)r * 1024 + i0 + c];
    }
    __syncthreads();

    // --- per-wave column FFT (column i0+w) ---------------------------------
    float2* d = colbuf + w * CSTR;
    int i = i0 + w;
    int kx = __brev((unsigned)i) >> 22;
    int fx = (kx < 512) ? kx : kx - 1024;
    float fx2 = (float)(fx * fx);

    for (int s = 9; s >= 0; --s) {
        int len = 1 << s, off = 1024 - 2 * len;
        asm volatile("s_waitcnt lgkmcnt(0)" ::: "memory");
        __builtin_amdgcn_sched_barrier(0);
        #pragma unroll
        for (int k = 0; k < 8; ++k) {
            int bt = lane + (k << 6);
            int j = bt & (len - 1);
            int ii = ((bt >> s) << (s + 1)) | j;
            float2 u = d[ii], v = d[ii + len], wv = twl[off + j];
            d[ii] = make_float2(u.x + v.x, u.y + v.y);
            float dr = u.x - v.x, di = u.y - v.y;
            d[ii + len] = make_float2(dr * wv.x - di * wv.y, dr * wv.y + di * wv.x);
        }
    }
    asm volatile("s_waitcnt lgkmcnt(0)" ::: "memory");
    __builtin_amdgcn_sched_barrier(0);
    const float cc = -1.0f / (4.0f * PI_F * PI_F * 1024.0f * 1024.0f); // incl. 1/(H*W)
    #pragma unroll
    for (int k = 0; k < 16; ++k) {
        int kk = lane + (k << 6);
        int ky = __brev((unsigned)kk) >> 22;
        int fy = (ky < 512) ? ky : ky - 1024;
        float k2 = fx2 + (float)(fy * fy);
        float s = (k2 > 0.0f) ? (cc / k2) : 0.0f;   // DC zeroed
        float2 v = d[kk];
        d[kk] = make_float2(v.x * s, v.y * s);
    }
    for (int s = 0; s <= 9; ++s) {
        int len = 1 << s, off = 1024 - 2 * len;
        asm volatile("s_waitcnt lgkmcnt(0)" ::: "memory");
        __builtin_amdgcn_sched_barrier(0);
        #pragma unroll
        for (int k = 0; k < 8; ++k) {
            int bt = lane + (k << 6);
            int j = bt & (len - 1);
            int ii = ((bt >> s) << (s + 1)) | j;
            float2 u = d[ii], v = d[ii + len], wv = twl[off + j];   // conj(w)
            float tr = v.x * wv.x + v.y * wv.y;
            float ti = v.y * wv.x - v.x * wv.y;
            d[ii] = make_float2(u.x + tr, u.y + ti);
            d[ii + len] = make_float2(u.x - tr, u.y - ti);
        }
    }
    asm volatile("s_waitcnt lgkmcnt(0)" ::: "memory");
    __builtin_amdgcn_sched_barrier(0);
    __syncthreads();

    #pragma unroll 4
    for (int pass = 0; pass < 16; ++pass) {
        int n = (pass << 9) + tid;
        int r = n >> 3, c = n & 7;
        g[(size_t)r * 1024 + i0 + c] = colbuf[c * CSTR + r];
    }
}

// ---------------------------------------------------------------------------
// Fused inverse row FFT + final projection. Band index XCD-swizzled.
// (round-9 proven configuration: float2 ring, DMA load, float4 emit)
// ---------------------------------------------------------------------------
#define FBAND 4

__global__ __launch_bounds__(256) void k_ifinal(const float2* __restrict__ spec,
                                                const float* __restrict__ UV,
                                                const float* __restrict__ X,
                                                float* __restrict__ out,
                                                const float2* __restrict__ tw)
{
    __shared__ __align__(16) float2 ring[3][1024];   // 24 KB
    __shared__ __align__(16) float2 twl[1024];       // 8 KB
    int bx = blockIdx.x, q = blockIdx.y;
    int band = (bx & 7) * 32 + (bx >> 3);   // XCD swizzle (256 % 8 == 0)
    int b0 = 2 * q, b1 = 2 * q + 1;
    int y0 = band * FBAND;
    int tid = threadIdx.x, w = tid >> 6, lane = tid & 63;

    for (int j = tid; j < 1024; j += 256) twl[j] = tw[j];

    size_t sbase = (size_t)q * HW;
    const float* u0 = UV + (size_t)(0 * BB + b0) * HW;
    const float* v0 = UV + (size_t)(BB + b0) * HW;
    const float* u1 = UV + (size_t)(0 * BB + b1) * HW;
    const float* v1 = UV + (size_t)(BB + b1) * HW;
    const float* p0 = X + (size_t)(b0 * 3 + 2) * HW;
    const float* p1 = X + (size_t)(b1 * 3 + 2) * HW;
    float* o_u0 = out + (size_t)(b0 * 3 + 0) * HW;
    float* o_v0 = out + (size_t)(b0 * 3 + 1) * HW;
    float* o_p0 = out + (size_t)(b0 * 3 + 2) * HW;
    float* o_u1 = out + (size_t)(b1 * 3 + 0) * HW;
    float* o_v1 = out + (size_t)(b1 * 3 + 1) * HW;
    float* o_p1 = out + (size_t)(b1 * 3 + 2) * HW;

    for (int rr = 0; rr < FBAND + 2; ++rr) {
        int yg = (y0 - 1 + rr) & (HH - 1);
        float2* slot = ring[rr % 3];

        __syncthreads();   // prior emit readers done before overwriting oldest slot
        const float* g = (const float*)(spec + sbase + (size_t)yg * 1024);
        for (int cch = w; cch < 8; cch += 4)
            gload16(g + (cch << 8) + (lane << 2), ((float*)slot) + (cch << 8) + (lane << 2));

        fft_dit_inv2(slot, twl);   // internal stage barriers drain DMA first
        __syncthreads();           // slot complete

        if (rr >= 2) {
            int ye = y0 + rr - 2;
            const float2* pcn = ring[(rr - 1) % 3];   // row ye
            const float2* ppm = ring[(rr - 2) % 3];   // row ye-1
            const float2* ppp = ring[rr % 3];         // row ye+1
            int xq = tid << 2;

            float4 cA = *(const float4*)&pcn[xq];
            float4 cB = *(const float4*)&pcn[xq + 2];
            float4 uA = *(const float4*)&ppm[xq];
            float4 uB = *(const float4*)&ppm[xq + 2];
            float4 dA = *(const float4*)&ppp[xq];
            float4 dB = *(const float4*)&ppp[xq + 2];
            float2 lf = pcn[(xq - 1) & 1023];
            float2 rt = pcn[(xq + 4) & 1023];

            float c0[4] = { cA.x, cA.z, cB.x, cB.z }, c1[4] = { cA.y, cA.w, cB.y, cB.w };
            float um0[4] = { uA.x, uA.z, uB.x, uB.z }, um1[4] = { uA.y, uA.w, uB.y, uB.w };
            float dp0[4] = { dA.x, dA.z, dB.x, dB.z }, dp1[4] = { dA.y, dA.w, dB.y, dB.w };
            float e0[6] = { lf.x, c0[0], c0[1], c0[2], c0[3], rt.x };
            float e1[6] = { lf.y, c1[0], c1[1], c1[2], c1[3], rt.y };

            size_t ro = (size_t)ye * WW + xq;
            float4 u0q = *(const float4*)(u0 + ro);
            float4 v0q = *(const float4*)(v0 + ro);
            float4 u1q = *(const float4*)(u1 + ro);
            float4 v1q = *(const float4*)(v1 + ro);
            float4 p0q = *(const float4*)(p0 + ro);
            float4 p1q = *(const float4*)(p1 + ro);

            float4 ou0, ov0, op0, ou1, ov1, op1;
            #pragma unroll
            for (int k = 0; k < 4; ++k) {
                ((float*)&ou0)[k] = ((float*)&u0q)[k] - 0.5f * (e0[k + 2] - e0[k]);
                ((float*)&ov0)[k] = ((float*)&v0q)[k] - 0.5f * (dp0[k] - um0[k]);
                ((float*)&op0)[k] = ((float*)&p0q)[k] + c0[k];
                ((float*)&ou1)[k] = ((float*)&u1q)[k] - 0.5f * (e1[k + 2] - e1[k]);
                ((float*)&ov1)[k] = ((float*)&v1q)[k] - 0.5f * (dp1[k] - um1[k]);
                ((float*)&op1)[k] = ((float*)&p1q)[k] + c1[k];
            }
            *(float4*)(o_u0 + ro) = ou0;
            *(float4*)(o_v0 + ro) = ov0;
            *(float4*)(o_p0 + ro) = op0;
            *(float4*)(o_u1 + ro) = ou1;
            *(float4*)(o_v1 + ro) = ov1;
            *(float4*)(o_p1 + ro) = op1;
        }
    }
}

extern "C" void kernel_launch(void* const* d_in, const int* in_sizes, int n_in,
                              void* d_out, int out_size, void* d_ws, size_t ws_size,
                              hipStream_t stream)
{
    const float* X    = (const float*)d_in[0];
    const float* beta = (const float*)d_in[1];
    const float* fu   = (const float*)d_in[2];
    const float* fv   = (const float*)d_in[3];
    float* out = (float*)d_out;
    float* ws  = (float*)d_ws;

    unsigned short* F1 = (unsigned short*)ws;     // 16M bf16 (32MB)
    float* UV  = ws + (size_t)BB * HW;            // 16M floats (64MB)
    float* Cbf = UV + (size_t)2 * BB * HW;        // 8M floats  (32MB)
    float* TWf = Cbf + (size_t)BB * HW;           // 2048 floats
    float* NRM = TWf + 2048;                      // 16 floats
    float2* Cb = (float2*)Cbf;
    float2* TW = (float2*)TWf;

    k_twid<<<4, 256, 0, stream>>>(TW, NRM);

    dim3 blk(256);

    k_diff3<<<2048, blk, 0, stream>>>(fu, fv, F1, NRM);
    k_star<<<dim3(HH, BB), blk, 0, stream>>>(X, beta, F1, NRM, UV);
    k_divfft<<<dim3(HH, BB / 2), blk, 0, stream>>>(UV, Cb, TW);
    k_colpass<<<dim3(WW / CT, 4), dim3(512), 0, stream>>>(Cb, TW);
    k_ifinal<<<dim3(HH / FBAND, BB / 2), blk, 0, stream>>>(Cb, UV, X, out, TW);
}